// Round 2
// baseline (218.972 us; speedup 1.0000x reference)
//
#include <hip/hip_runtime.h>
#include <hip/hip_bf16.h>
#include <stdint.h>

// VQ nearest-neighbor: B=8192 rows z[256] vs K=8192 embeddings[256] (f32).
// fp16 split-GEMM (zh*eh + (zh*el' + zl'*eh)/2048) fused with per-row,
// per-64-col-chunk argmin of (e_sq - 2*cross); exact f64 re-rank of top-4
// chunk winners; gather winning embedding row.

#define NB 8192
#define NK 8192
#define ND 256
#define NCHUNK (NK / 64)   // 128 candidate chunks per row

typedef __attribute__((ext_vector_type(4))) _Float16 half4;
typedef __attribute__((ext_vector_type(8))) _Float16 half8;
typedef __attribute__((ext_vector_type(4))) float f32x4;

__device__ __forceinline__ unsigned int fkey(float f) {
  unsigned int i = __float_as_uint(f);
  return (i & 0x80000000u) ? ~i : (i | 0x80000000u);  // monotone map f32 -> u32
}

__device__ __forceinline__ void gload_lds16(const void* g, void* l) {
  __builtin_amdgcn_global_load_lds(
      (const __attribute__((address_space(1))) unsigned int*)g,
      (__attribute__((address_space(3))) unsigned int*)l, 16, 0, 0);
}

// ---------------- prep: split f32 -> f16 hi + 2048*lo ----------------
__global__ __launch_bounds__(256) void prep_split(
    const float4* __restrict__ z4, const float4* __restrict__ e4,
    half4* __restrict__ zh, half4* __restrict__ zl,
    half4* __restrict__ eh, half4* __restrict__ el) {
  int i = blockIdx.x * 256 + threadIdx.x;
  const int NZ = (NB * ND) / 4;
  const float4* s;
  half4 *dh, *dl;
  int j;
  if (i < NZ) { s = z4; dh = zh; dl = zl; j = i; }
  else        { s = e4; dh = eh; dl = el; j = i - NZ; }
  float4 v = s[j];
  half4 h, l;
  h.x = (_Float16)v.x; l.x = (_Float16)((v.x - (float)h.x) * 2048.0f);
  h.y = (_Float16)v.y; l.y = (_Float16)((v.y - (float)h.y) * 2048.0f);
  h.z = (_Float16)v.z; l.z = (_Float16)((v.z - (float)h.z) * 2048.0f);
  h.w = (_Float16)v.w; l.w = (_Float16)((v.w - (float)h.w) * 2048.0f);
  dh[j] = h;
  dl[j] = l;
}

// ---------------- e_sq (f64 accumulate) ----------------
__global__ __launch_bounds__(256) void esq_kernel(const float* __restrict__ e,
                                                  float* __restrict__ esq) {
  int row = blockIdx.x * 4 + (threadIdx.x >> 6);
  int lane = threadIdx.x & 63;
  float4 v = ((const float4*)(e + (size_t)row * ND))[lane];
  double s = (double)v.x * v.x + (double)v.y * v.y + (double)v.z * v.z +
             (double)v.w * v.w;
#pragma unroll
  for (int sh = 1; sh < 64; sh <<= 1) s += __shfl_xor(s, sh, 64);
  if (lane == 0) esq[row] = (float)s;
}

// ---------------- fused split-GEMM + per-chunk argmin ----------------
__global__ __launch_bounds__(256, 2) void gemm_argmin(
    const _Float16* __restrict__ zh, const _Float16* __restrict__ zl,
    const _Float16* __restrict__ eh, const _Float16* __restrict__ el,
    const float* __restrict__ esq, unsigned long long* __restrict__ cand) {
  __shared__ __align__(16) _Float16 sAh[128 * 32];
  __shared__ __align__(16) _Float16 sAl[128 * 32];
  __shared__ __align__(16) _Float16 sBh[128 * 32];
  __shared__ __align__(16) _Float16 sBl[128 * 32];
  const int tid = threadIdx.x;
  const int wave = tid >> 6, lane = tid & 63;
  const int bx = blockIdx.x, by = blockIdx.y;
  const int wr = wave >> 1, wc = wave & 1;
  const int row0 = by * 128, col0 = bx * 128;

  f32x4 acc1[4][4] = {};  // zh*eh
  f32x4 acc2[4][4] = {};  // zh*el' + zl'*eh   (scaled by 2048)

  const int fr = lane & 15;
  const int fk = (lane >> 4) * 8;

  for (int ks = 0; ks < 8; ++ks) {
    const int kc = ks * 32;
    __syncthreads();
    // stage 4 tiles of [128 rows x 32 k] f16; 512 16B-chunks per tile total
#pragma unroll
    for (int i = 0; i < 2; ++i) {
      const int base = wave * 128 + i * 64;     // wave-uniform 16B-chunk index
      const int chunk = base + lane;            // per-lane chunk id
      const int r = chunk >> 2, c8 = (chunk & 3) * 8;
      const size_t loff = (size_t)base * 8;     // LDS element offset (wave-uniform)
      gload_lds16(zh + (size_t)(row0 + r) * ND + kc + c8, sAh + loff);
      gload_lds16(zl + (size_t)(row0 + r) * ND + kc + c8, sAl + loff);
      gload_lds16(eh + (size_t)(col0 + r) * ND + kc + c8, sBh + loff);
      gload_lds16(el + (size_t)(col0 + r) * ND + kc + c8, sBl + loff);
    }
    __syncthreads();

    half8 ah[4], al[4], bh[4], bl[4];
#pragma unroll
    for (int m = 0; m < 4; ++m) {
      int r = wr * 64 + m * 16 + fr;
      ah[m] = *(const half8*)&sAh[r * 32 + fk];
      al[m] = *(const half8*)&sAl[r * 32 + fk];
    }
#pragma unroll
    for (int n = 0; n < 4; ++n) {
      int c = wc * 64 + n * 16 + fr;
      bh[n] = *(const half8*)&sBh[c * 32 + fk];
      bl[n] = *(const half8*)&sBl[c * 32 + fk];
    }
#pragma unroll
    for (int m = 0; m < 4; ++m)
#pragma unroll
      for (int n = 0; n < 4; ++n) {
        acc1[m][n] = __builtin_amdgcn_mfma_f32_16x16x32_f16(ah[m], bh[n], acc1[m][n], 0, 0, 0);
        acc2[m][n] = __builtin_amdgcn_mfma_f32_16x16x32_f16(ah[m], bl[n], acc2[m][n], 0, 0, 0);
        acc2[m][n] = __builtin_amdgcn_mfma_f32_16x16x32_f16(al[m], bh[n], acc2[m][n], 0, 0, 0);
      }
  }

  // epilogue: dist = esq[col] - 2*(acc1 + acc2/2048); per-row min over 64 cols
  float es[4];
#pragma unroll
  for (int n = 0; n < 4; ++n) es[n] = esq[col0 + wc * 64 + n * 16 + fr];
  const int chunkIdx = bx * 2 + wc;
#pragma unroll
  for (int m = 0; m < 4; ++m) {
#pragma unroll
    for (int j = 0; j < 4; ++j) {
      unsigned long long best = ~0ull;
#pragma unroll
      for (int n = 0; n < 4; ++n) {
        float cross = acc1[m][n][j] + acc2[m][n][j] * (1.0f / 2048.0f);
        float dist = es[n] - 2.0f * cross;
        unsigned int col = col0 + wc * 64 + n * 16 + fr;
        unsigned long long p = ((unsigned long long)fkey(dist) << 32) | col;
        best = p < best ? p : best;
      }
#pragma unroll
      for (int s = 1; s < 16; s <<= 1) {
        unsigned long long o = __shfl_xor(best, s, 64);
        best = o < best ? o : best;
      }
      if ((lane & 15) == 0) {
        int row = row0 + wr * 64 + m * 16 + (lane >> 4) * 4 + j;
        cand[(size_t)row * NCHUNK + chunkIdx] = best;
      }
    }
  }
}

// ---------------- re-rank top-4 chunk winners exactly (f64), gather ----------------
__global__ __launch_bounds__(256) void rerank(
    const unsigned long long* __restrict__ cand, const float* __restrict__ z,
    const float* __restrict__ e, float* __restrict__ out) {
  const int row = blockIdx.x;
  const int tid = threadIdx.x, wave = tid >> 6, lane = tid & 63;
  __shared__ unsigned long long sc[NCHUNK];
  __shared__ int sidx[4];
  __shared__ double sdist[4];
  __shared__ int sbest;
  if (tid < NCHUNK) sc[tid] = cand[(size_t)row * NCHUNK + tid];
  __syncthreads();
  if (wave == 0) {
    unsigned long long v0 = sc[lane], v1 = sc[lane + 64];
    for (int r = 0; r < 4; ++r) {
      unsigned long long mn = v0 < v1 ? v0 : v1;
#pragma unroll
      for (int s = 1; s < 64; s <<= 1) {
        unsigned long long o = __shfl_xor(mn, s, 64);
        mn = o < mn ? o : mn;
      }
      if (lane == 0) sidx[r] = (int)(mn & 0xFFFFFFFFu);
      if (v0 == mn) v0 = ~0ull;
      if (v1 == mn) v1 = ~0ull;
    }
  }
  __syncthreads();
  {
    int idx = sidx[wave];
    double s = 0.0;
#pragma unroll
    for (int t = 0; t < 4; ++t) {
      int d = lane * 4 + t;
      double diff = (double)z[(size_t)row * ND + d] - (double)e[(size_t)idx * ND + d];
      s += diff * diff;
    }
#pragma unroll
    for (int sh = 1; sh < 64; sh <<= 1) s += __shfl_xor(s, sh, 64);
    if (lane == 0) sdist[wave] = s;
  }
  __syncthreads();
  if (tid == 0) {
    double bd = sdist[0];
    int bi = sidx[0];
    for (int w = 1; w < 4; ++w) {
      if (sdist[w] < bd || (sdist[w] == bd && sidx[w] < bi)) { bd = sdist[w]; bi = sidx[w]; }
    }
    sbest = bi;
  }
  __syncthreads();
  out[(size_t)row * ND + tid] = e[(size_t)sbest * ND + tid];
}

extern "C" void kernel_launch(void* const* d_in, const int* in_sizes, int n_in,
                              void* d_out, int out_size, void* d_ws, size_t ws_size,
                              hipStream_t stream) {
  const float* z = (const float*)d_in[0];
  const float* e = (const float*)d_in[1];
  float* out = (float*)d_out;
  char* ws = (char*)d_ws;

  _Float16* zh = (_Float16*)ws;                       // 4 MB
  _Float16* zl = zh + (size_t)NB * ND;                // 4 MB
  _Float16* eh = zl + (size_t)NB * ND;                // 4 MB
  _Float16* el = eh + (size_t)NK * ND;                // 4 MB
  float* esq = (float*)(ws + 16u * 1024 * 1024);      // 32 KB
  unsigned long long* cand =
      (unsigned long long*)(ws + 16u * 1024 * 1024 + 65536);  // 8 MB

  prep_split<<<((NB + NK) * ND / 4) / 256, 256, 0, stream>>>(
      (const float4*)z, (const float4*)e, (half4*)zh, (half4*)zl, (half4*)eh,
      (half4*)el);
  esq_kernel<<<NK / 4, 256, 0, stream>>>(e, esq);
  gemm_argmin<<<dim3(NK / 128, NB / 128), 256, 0, stream>>>(zh, zl, eh, el, esq, cand);
  rerank<<<NB, 256, 0, stream>>>(cand, z, e, out);
}